// Round 1
// baseline (661.911 us; speedup 1.0000x reference)
//
#include <hip/hip_runtime.h>

#define SS 192
#define DD 128
#define SAN 16384                     // stage-A row length (128*128)
#define PITCH 136                     // LDS row pitch in bf16 elements (272B, 16B-aligned, conflict-safe)

typedef short bf8v __attribute__((ext_vector_type(8)));   // 8 x bf16
typedef float f4v  __attribute__((ext_vector_type(4)));

__device__ __forceinline__ unsigned short f2bf(float f) {
    union { float f; unsigned u; } v; v.f = f;
    unsigned r = v.u + 0x7fffu + ((v.u >> 16) & 1u);
    return (unsigned short)(r >> 16);
}

__device__ __forceinline__ f4v mfma16(bf8v a, bf8v b, f4v c) {
    return __builtin_amdgcn_mfma_f32_16x16x32_bf16(a, b, c, 0, 0, 0);
}

// ---------------- K0: MLP projections -> bf16 P / SH / ST (384x128) -------------
__global__ __launch_bounds__(256) void proj_kernel(
    const float* __restrict__ x,
    const float* __restrict__ Wp, const float* __restrict__ bp,
    const float* __restrict__ Wh, const float* __restrict__ bh,
    const float* __restrict__ Wt, const float* __restrict__ bt,
    unsigned short* __restrict__ Pb, unsigned short* __restrict__ SHb,
    unsigned short* __restrict__ STb)
{
    __shared__ float xs[8 * 1024];
    int r0 = blockIdx.x * 8;
    int w  = blockIdx.y;
    const float* W    = (w == 0) ? Wp : (w == 1) ? Wh : Wt;
    const float* bias = (w == 0) ? bp : (w == 1) ? bh : bt;
    unsigned short* O = (w == 0) ? Pb : (w == 1) ? SHb : STb;
    int tid = threadIdx.x;
    for (int u = tid; u < 2048; u += 256)
        *(float4*)(&xs[u * 4]) = *(const float4*)(&x[(size_t)r0 * 1024 + (size_t)u * 4]);
    __syncthreads();
    int col = tid & 127, rg = tid >> 7;
    float acc[4] = {0.f, 0.f, 0.f, 0.f};
    for (int k = 0; k < 1024; ++k) {
        float wv = W[(size_t)k * 128 + col];
        #pragma unroll
        for (int r = 0; r < 4; ++r) acc[r] += xs[(rg * 4 + r) * 1024 + k] * wv;
    }
    float bb = bias[col];
    #pragma unroll
    for (int r = 0; r < 4; ++r) {
        float v = acc[r] + bb;
        v = v > 0.f ? v : 0.1f * v;
        O[(size_t)(r0 + rg * 4 + r) * 128 + col] = f2bf(v);
    }
}

// ---------------- K1a: W[i][k][j] -> Wprep[j][i][k] (bf16), slots {0,1,2,3,5} ---
__global__ __launch_bounds__(256) void prep_rev(
    const float* __restrict__ w0, const float* __restrict__ w1,
    const float* __restrict__ w2, const float* __restrict__ w3,
    const float* __restrict__ w5, unsigned short* __restrict__ Wprep)
{
    __shared__ float tile[32][33];
    int sel = blockIdx.z;
    const float* in = (sel == 0) ? w0 : (sel == 1) ? w1 : (sel == 2) ? w2 : (sel == 3) ? w3 : w5;
    int slot = (sel == 4) ? 5 : sel;
    unsigned short* out = Wprep + (size_t)slot * 2097152;
    int i  = blockIdx.y;
    int kt = (blockIdx.x >> 2) * 32, jt = (blockIdx.x & 3) * 32;
    int tx = threadIdx.x & 31, ty = threadIdx.x >> 5;
    #pragma unroll
    for (int r = 0; r < 4; ++r) {
        int k = kt + ty + r * 8;
        tile[ty + r * 8][tx] = in[((size_t)i * 128 + k) * 128 + jt + tx];
    }
    __syncthreads();
    #pragma unroll
    for (int r = 0; r < 4; ++r) {
        int j = jt + ty + r * 8;
        out[((size_t)j * 128 + i) * 128 + kt + tx] = f2bf(tile[tx][ty + r * 8]);
    }
}

// ---------------- K1b: W[i][k][j] -> Wprep[j][k][i] (bf16), slot 4 (ph_cop) ----
__global__ __launch_bounds__(256) void prep_cop(
    const float* __restrict__ in, unsigned short* __restrict__ Wprep)
{
    __shared__ float tile[32][33];
    unsigned short* out = Wprep + (size_t)4 * 2097152;
    int k  = blockIdx.y;
    int it = (blockIdx.x >> 2) * 32, jt = (blockIdx.x & 3) * 32;
    int tx = threadIdx.x & 31, ty = threadIdx.x >> 5;
    #pragma unroll
    for (int r = 0; r < 4; ++r) {
        int i = it + ty + r * 8;
        tile[ty + r * 8][tx] = in[((size_t)i * 128 + k) * 128 + jt + tx];
    }
    __syncthreads();
    #pragma unroll
    for (int r = 0; r < 4; ++r) {
        int j = jt + ty + r * 8;
        out[((size_t)j * 128 + k) * 128 + it + tx] = f2bf(tile[tx][ty + r * 8]);
    }
}

// ---------------- K2: stage A GEMMs: SA[slot] (384x16384) = A(384x128)@Wprep^T --
__global__ __launch_bounds__(256) void stageA(
    const unsigned short* __restrict__ Pb, const unsigned short* __restrict__ STb,
    const unsigned short* __restrict__ Wprep, unsigned short* __restrict__ SAout)
{
    __shared__ unsigned short BL[64 * PITCH];
    int slot = blockIdx.y;
    int n0 = blockIdx.x * 64;
    const unsigned short* A  = (slot == 5) ? STb : Pb;
    const unsigned short* Wn = Wprep + (size_t)slot * 2097152 + (size_t)n0 * 128;
    unsigned short* Oo = SAout + (size_t)slot * ((size_t)384 * SAN);
    int tid = threadIdx.x;
    for (int u = tid; u < 1024; u += 256) {
        int e = u * 8; int r = e >> 7; int c = e & 127;
        *(uint4*)(&BL[r * PITCH + c]) = *(const uint4*)(&Wn[e]);
    }
    __syncthreads();
    int wave = tid >> 6, lane = tid & 63, m = lane & 15, quad = lane >> 4;
    const unsigned short* br = &BL[(wave * 16 + m) * PITCH + quad * 8];
    bf8v b0 = *(const bf8v*)(br);
    bf8v b1 = *(const bf8v*)(br + 32);
    bf8v b2 = *(const bf8v*)(br + 64);
    bf8v b3 = *(const bf8v*)(br + 96);
    for (int mt = 0; mt < 24; ++mt) {
        const unsigned short* ar = A + (size_t)(mt * 16 + m) * 128 + quad * 8;
        f4v acc = {0.f, 0.f, 0.f, 0.f};
        acc = mfma16(*(const bf8v*)(ar),      b0, acc);
        acc = mfma16(*(const bf8v*)(ar + 32), b1, acc);
        acc = mfma16(*(const bf8v*)(ar + 64), b2, acc);
        acc = mfma16(*(const bf8v*)(ar + 96), b3, acc);
        unsigned short* orow = Oo + (size_t)(mt * 16) * SAN + n0 + wave * 16;
        #pragma unroll
        for (int r = 0; r < 4; ++r)
            orow[(size_t)(quad * 4 + r) * SAN + m] = f2bf(acc[r]);
    }
}

// ---------------- K3: stage B for the 5 symmetric triaffines -------------------
// block = (bz, t); computes G = (X @ wz) @ Y^T for slice (b,z), applies sym,
// writes [b,z,x,y] contiguous (t<4 -> d_out segment t; t==4 (pt_cop) -> tri_ws).
__global__ __launch_bounds__(256) void stageB_sym(
    const unsigned short* __restrict__ Pb, const unsigned short* __restrict__ SHb,
    const unsigned short* __restrict__ STb, const unsigned short* __restrict__ SA,
    float* __restrict__ out, float* __restrict__ tri_ws, int tbase)
{
    __shared__ unsigned short WZT[128 * PITCH];
    __shared__ unsigned short Tst[64 * PITCH];
    const size_t OUTN = (size_t)2 * SS * SS * SS;

    int t  = tbase + blockIdx.y;
    int bz = blockIdx.x;
    int b  = bz / SS;

    int slot; const unsigned short *X, *Y; float* O;
    if (t == 0)      { slot = 0; X = SHb; Y = STb; O = out + (size_t)bz * SS * SS; }
    else if (t == 1) { slot = 1; X = SHb; Y = STb; O = out + OUTN + (size_t)bz * SS * SS; }
    else if (t == 2) { slot = 2; X = SHb; Y = SHb; O = out + 2 * OUTN + (size_t)bz * SS * SS; }
    else if (t == 3) { slot = 3; X = STb; Y = STb; O = out + 3 * OUTN + (size_t)bz * SS * SS; }
    else             { slot = 5; X = Pb;  Y = Pb;  O = tri_ws + (size_t)bz * SS * SS; }

    const unsigned short* src = SA + ((size_t)slot * 384 + bz) * SAN;
    int tid = threadIdx.x;
    for (int u = tid; u < 2048; u += 256) {
        int e = u * 8; int j = e >> 7; int i = e & 127;
        *(uint4*)(&WZT[j * PITCH + i]) = *(const uint4*)(&src[e]);
    }
    __syncthreads();

    int wave = tid >> 6, lane = tid & 63, m = lane & 15, quad = lane >> 4;
    // balanced upper-triangle m-tile assignment: tiles(mt) = 12-mt
    const int mt_tab[4][3] = {{0,7,9},{1,6,8},{2,5,10},{3,4,11}};

    const unsigned short* Xb = X + (size_t)b * SS * DD;
    const unsigned short* Yb = Y + (size_t)b * SS * DD;
    unsigned short* Trow = &Tst[wave * 16 * PITCH];
    const unsigned short* Ta = &Tst[(wave * 16 + m) * PITCH + quad * 8];

    for (int mi = 0; mi < 3; ++mi) {
        int mt = mt_tab[wave][mi];
        // A-fragments of X stripe (global, contiguous 16B per lane)
        const unsigned short* xr = Xb + (size_t)(mt * 16 + m) * DD + quad * 8;
        bf8v a[4];
        a[0] = *(const bf8v*)(xr);
        a[1] = *(const bf8v*)(xr + 32);
        a[2] = *(const bf8v*)(xr + 64);
        a[3] = *(const bf8v*)(xr + 96);

        // phase 1: T stripe (16 x 128) = X_stripe @ wz
        for (int nt = 0; nt < 8; nt += 2) {
            f4v acc0 = {0.f,0.f,0.f,0.f}, acc1 = {0.f,0.f,0.f,0.f};
            #pragma unroll
            for (int kk = 0; kk < 4; ++kk) {
                const unsigned short* bp0 = &WZT[(nt * 16 + m) * PITCH + kk * 32 + quad * 8];
                const unsigned short* bp1 = &WZT[((nt + 1) * 16 + m) * PITCH + kk * 32 + quad * 8];
                acc0 = mfma16(a[kk], *(const bf8v*)bp0, acc0);
                acc1 = mfma16(a[kk], *(const bf8v*)bp1, acc1);
            }
            #pragma unroll
            for (int r = 0; r < 4; ++r) {
                Trow[(quad * 4 + r) * PITCH + nt * 16 + m]       = f2bf(acc0[r]);
                Trow[(quad * 4 + r) * PITCH + (nt + 1) * 16 + m] = f2bf(acc1[r]);
            }
        }
        // reload T stripe as A-fragments (wave-local LDS dependency)
        // A-operand layout: lane m holds A[m][kk*32 + quad*8 + 0..7]
        bf8v ta[4];
        ta[0] = *(const bf8v*)(Ta);
        ta[1] = *(const bf8v*)(Ta + 32);
        ta[2] = *(const bf8v*)(Ta + 64);
        ta[3] = *(const bf8v*)(Ta + 96);

        // phase 2: G tiles (mt, yt) for yt >= mt, sym double-write
        for (int yt = mt; yt < 12; ++yt) {
            f4v acc = {0.f,0.f,0.f,0.f};
            #pragma unroll
            for (int kk = 0; kk < 4; ++kk) {
                bf8v bv = *(const bf8v*)(Yb + (size_t)(yt * 16 + m) * DD + kk * 32 + quad * 8);
                acc = mfma16(ta[kk], bv, acc);
            }
            int xs_ = mt * 16, ys_ = yt * 16, cc = m;
            if (yt > mt) {
                #pragma unroll
                for (int r = 0; r < 4; ++r)
                    O[(size_t)(xs_ + quad * 4 + r) * SS + ys_ + cc] = acc[r];
                *(f4v*)(&O[(size_t)(ys_ + cc) * SS + xs_ + quad * 4]) = acc;
            } else {
                #pragma unroll
                for (int r = 0; r < 4; ++r) {
                    int rr = quad * 4 + r;
                    if (rr <= cc) O[(size_t)(xs_ + rr) * SS + ys_ + cc] = acc[r];
                    if (cc > rr)  O[(size_t)(ys_ + cc) * SS + xs_ + rr] = acc[r];
                }
            }
        }
    }
}

// ---------------- K5: ph_cop stage B: out[b,x,y,z] contiguous per (b,x) --------
__global__ __launch_bounds__(256) void stageB_cop(
    const unsigned short* __restrict__ Pb, const unsigned short* __restrict__ SHb,
    const unsigned short* __restrict__ SA4, float* __restrict__ out4)
{
    __shared__ unsigned short MT[128 * PITCH];
    __shared__ unsigned short Tst[64 * PITCH];
    int bx = blockIdx.x;
    int b  = bx / SS;
    float* O = out4 + (size_t)bx * SS * SS;

    const unsigned short* src = SA4 + (size_t)bx * SAN;
    int tid = threadIdx.x;
    for (int u = tid; u < 2048; u += 256) {
        int e = u * 8; int j = e >> 7; int k = e & 127;
        *(uint4*)(&MT[j * PITCH + k]) = *(const uint4*)(&src[e]);
    }
    __syncthreads();

    int wave = tid >> 6, lane = tid & 63, m = lane & 15, quad = lane >> 4;
    unsigned short* Trow = &Tst[wave * 16 * PITCH];
    const unsigned short* Tb = &Tst[(wave * 16 + m) * PITCH + quad * 8];

    for (int zi = 0; zi < 3; ++zi) {
        int zt = wave * 3 + zi;
        // A-fragments: SH rows (z stripe)
        const unsigned short* sr = SHb + (size_t)(b * SS + zt * 16 + m) * DD + quad * 8;
        bf8v a[4];
        a[0] = *(const bf8v*)(sr);
        a[1] = *(const bf8v*)(sr + 32);
        a[2] = *(const bf8v*)(sr + 64);
        a[3] = *(const bf8v*)(sr + 96);
        // phase 1: T[z,j] stripe = SH_stripe @ M
        for (int jt = 0; jt < 8; jt += 2) {
            f4v acc0 = {0.f,0.f,0.f,0.f}, acc1 = {0.f,0.f,0.f,0.f};
            #pragma unroll
            for (int kk = 0; kk < 4; ++kk) {
                const unsigned short* bp0 = &MT[(jt * 16 + m) * PITCH + kk * 32 + quad * 8];
                const unsigned short* bp1 = &MT[((jt + 1) * 16 + m) * PITCH + kk * 32 + quad * 8];
                acc0 = mfma16(a[kk], *(const bf8v*)bp0, acc0);
                acc1 = mfma16(a[kk], *(const bf8v*)bp1, acc1);
            }
            #pragma unroll
            for (int r = 0; r < 4; ++r) {
                Trow[(quad * 4 + r) * PITCH + jt * 16 + m]       = f2bf(acc0[r]);
                Trow[(quad * 4 + r) * PITCH + (jt + 1) * 16 + m] = f2bf(acc1[r]);
            }
        }
        // T stripe as B-fragments (n = z); lane n holds B[kk*32+quad*8+0..7][n]
        bf8v tb[4];
        tb[0] = *(const bf8v*)(Tb);
        tb[1] = *(const bf8v*)(Tb + 32);
        tb[2] = *(const bf8v*)(Tb + 64);
        tb[3] = *(const bf8v*)(Tb + 96);
        // phase 2: G[y,z] = P @ T^T
        for (int yt = 0; yt < 12; ++yt) {
            f4v acc = {0.f,0.f,0.f,0.f};
            #pragma unroll
            for (int kk = 0; kk < 4; ++kk) {
                bf8v av = *(const bf8v*)(Pb + (size_t)(b * SS + yt * 16 + m) * DD + kk * 32 + quad * 8);
                acc = mfma16(av, tb[kk], acc);
            }
            #pragma unroll
            for (int r = 0; r < 4; ++r)
                O[(size_t)(yt * 16 + quad * 4 + r) * SS + zt * 16 + m] = acc[r];
        }
    }
}

// ---------------- K4: pt_cop transpose: [b,z,xy] -> [b,xy,z] -------------------
__global__ __launch_bounds__(256) void transpose_cop(
    const float* __restrict__ tri, float* __restrict__ out5)
{
    __shared__ float tile[64][65];
    int b  = blockIdx.z;
    int z0 = blockIdx.y * 64;
    int q0 = blockIdx.x * 64;
    const float* src = tri + (size_t)b * SS * 36864;
    float* dst = out5 + (size_t)b * 36864 * SS;
    int tx = threadIdx.x & 63, ty = threadIdx.x >> 6;
    #pragma unroll
    for (int r = 0; r < 16; ++r) {
        int z = z0 + ty + r * 4;
        if (z < SS) tile[ty + r * 4][tx] = src[(size_t)z * 36864 + q0 + tx];
    }
    __syncthreads();
    #pragma unroll
    for (int r = 0; r < 16; ++r) {
        int q = q0 + ty + r * 4;
        if (z0 + tx < SS) dst[(size_t)q * SS + z0 + tx] = tile[tx][ty + r * 4];
    }
}

extern "C" void kernel_launch(void* const* d_in, const int* in_sizes, int n_in,
                              void* d_out, int out_size, void* d_ws, size_t ws_size,
                              hipStream_t stream)
{
    const float* x   = (const float*)d_in[0];
    const float* Wp  = (const float*)d_in[1];
    const float* bp  = (const float*)d_in[2];
    const float* Wh  = (const float*)d_in[3];
    const float* bh  = (const float*)d_in[4];
    const float* Wt  = (const float*)d_in[5];
    const float* bt  = (const float*)d_in[6];
    const float* W_span_ph = (const float*)d_in[7];
    const float* W_span_pt = (const float*)d_in[8];
    const float* W_ph_sib  = (const float*)d_in[9];
    const float* W_pt_sib  = (const float*)d_in[10];
    const float* W_ph_cop  = (const float*)d_in[11];
    const float* W_pt_cop  = (const float*)d_in[12];

    char* ws = (char*)d_ws;
    unsigned short* Pb    = (unsigned short*)ws;                 // 98304 B
    unsigned short* SHb   = Pb + 384 * 128;
    unsigned short* STb   = SHb + 384 * 128;
    unsigned short* Wprep = (unsigned short*)(ws + 294912);      // 6 x 4 MiB bf16
    unsigned short* SA    = (unsigned short*)(ws + 294912 + (size_t)6 * 2097152 * 2);
    float* tri = (float*)SA;   // pt_cop symmetrized tensor overlays SA slots 0..4
                               // (safe: consumed before stageB_sym(t=4) runs)

    float* out  = (float*)d_out;
    const size_t OUTN = (size_t)2 * SS * SS * SS;

    proj_kernel<<<dim3(48, 3), 256, 0, stream>>>(x, Wp, bp, Wh, bh, Wt, bt, Pb, SHb, STb);
    prep_rev<<<dim3(16, 128, 5), 256, 0, stream>>>(W_span_ph, W_span_pt, W_ph_sib,
                                                   W_pt_sib, W_pt_cop, Wprep);
    prep_cop<<<dim3(16, 128), 256, 0, stream>>>(W_ph_cop, Wprep);
    stageA<<<dim3(256, 6), 256, 0, stream>>>(Pb, STb, Wprep, SA);
    // 4 sym triaffines straight to d_out
    stageB_sym<<<dim3(384, 4), 256, 0, stream>>>(Pb, SHb, STb, SA, out, tri, 0);
    // ph_cop (reads SA slot 4) before tri overlay is written
    stageB_cop<<<dim3(384), 256, 0, stream>>>(Pb, SHb, SA + (size_t)4 * 384 * SAN,
                                              out + 4 * OUTN);
    // pt_cop: sym slice into tri workspace (overlays SA slots 0..4; reads slot 5)
    stageB_sym<<<dim3(384, 1), 256, 0, stream>>>(Pb, SHb, STb, SA, out, tri, 4);
    transpose_cop<<<dim3(576, 3, 2), 256, 0, stream>>>(tri, out + 5 * OUTN);
}

// Round 2
// 640.914 us; speedup vs baseline: 1.0328x; 1.0328x over previous
//
#include <hip/hip_runtime.h>

#define SS 192
#define DD 128
#define SAN 16384                     // stage-A row length (128*128)
#define PITCH 136                     // LDS row pitch in bf16 elements (272B, 16B-aligned, conflict-safe)

typedef short bf8v __attribute__((ext_vector_type(8)));   // 8 x bf16
typedef float f4v  __attribute__((ext_vector_type(4)));

__device__ __forceinline__ unsigned short f2bf(float f) {
    union { float f; unsigned u; } v; v.f = f;
    unsigned r = v.u + 0x7fffu + ((v.u >> 16) & 1u);
    return (unsigned short)(r >> 16);
}

__device__ __forceinline__ f4v mfma16(bf8v a, bf8v b, f4v c) {
    return __builtin_amdgcn_mfma_f32_16x16x32_bf16(a, b, c, 0, 0, 0);
}

// ---------------- K0: MLP projections -> bf16 P / SH / ST (384x128) -------------
__global__ __launch_bounds__(256) void proj_kernel(
    const float* __restrict__ x,
    const float* __restrict__ Wp, const float* __restrict__ bp,
    const float* __restrict__ Wh, const float* __restrict__ bh,
    const float* __restrict__ Wt, const float* __restrict__ bt,
    unsigned short* __restrict__ Pb, unsigned short* __restrict__ SHb,
    unsigned short* __restrict__ STb)
{
    __shared__ float xs[8 * 1024];
    int r0 = blockIdx.x * 8;
    int w  = blockIdx.y;
    const float* W    = (w == 0) ? Wp : (w == 1) ? Wh : Wt;
    const float* bias = (w == 0) ? bp : (w == 1) ? bh : bt;
    unsigned short* O = (w == 0) ? Pb : (w == 1) ? SHb : STb;
    int tid = threadIdx.x;
    for (int u = tid; u < 2048; u += 256)
        *(float4*)(&xs[u * 4]) = *(const float4*)(&x[(size_t)r0 * 1024 + (size_t)u * 4]);
    __syncthreads();
    int col = tid & 127, rg = tid >> 7;
    float acc[4] = {0.f, 0.f, 0.f, 0.f};
    for (int k = 0; k < 1024; ++k) {
        float wv = W[(size_t)k * 128 + col];
        #pragma unroll
        for (int r = 0; r < 4; ++r) acc[r] += xs[(rg * 4 + r) * 1024 + k] * wv;
    }
    float bb = bias[col];
    #pragma unroll
    for (int r = 0; r < 4; ++r) {
        float v = acc[r] + bb;
        v = v > 0.f ? v : 0.1f * v;
        O[(size_t)(r0 + rg * 4 + r) * 128 + col] = f2bf(v);
    }
}

// ---------------- K1a: W[i][k][j] -> Wprep[j][i][k] (bf16), slots 0..3 ----------
__global__ __launch_bounds__(256) void prep_rev(
    const float* __restrict__ w0, const float* __restrict__ w1,
    const float* __restrict__ w2, const float* __restrict__ w3,
    unsigned short* __restrict__ Wprep)
{
    __shared__ float tile[32][33];
    int sel = blockIdx.z;
    const float* in = (sel == 0) ? w0 : (sel == 1) ? w1 : (sel == 2) ? w2 : w3;
    unsigned short* out = Wprep + (size_t)sel * 2097152;
    int i  = blockIdx.y;
    int kt = (blockIdx.x >> 2) * 32, jt = (blockIdx.x & 3) * 32;
    int tx = threadIdx.x & 31, ty = threadIdx.x >> 5;
    #pragma unroll
    for (int r = 0; r < 4; ++r) {
        int k = kt + ty + r * 8;
        tile[ty + r * 8][tx] = in[((size_t)i * 128 + k) * 128 + jt + tx];
    }
    __syncthreads();
    #pragma unroll
    for (int r = 0; r < 4; ++r) {
        int j = jt + ty + r * 8;
        out[((size_t)j * 128 + i) * 128 + kt + tx] = f2bf(tile[tx][ty + r * 8]);
    }
}

// ---------------- K1b: W[i][k][j] -> Wprep[j][k][i] (bf16), slots 4 (ph), 5 (pt)
__global__ __launch_bounds__(256) void prep_cop(
    const float* __restrict__ in0, const float* __restrict__ in1,
    unsigned short* __restrict__ Wprep)
{
    __shared__ float tile[32][33];
    int sel = blockIdx.z;
    const float* in = sel ? in1 : in0;
    unsigned short* out = Wprep + (size_t)(4 + sel) * 2097152;
    int k  = blockIdx.y;
    int it = (blockIdx.x >> 2) * 32, jt = (blockIdx.x & 3) * 32;
    int tx = threadIdx.x & 31, ty = threadIdx.x >> 5;
    #pragma unroll
    for (int r = 0; r < 4; ++r) {
        int i = it + ty + r * 8;
        tile[ty + r * 8][tx] = in[((size_t)i * 128 + k) * 128 + jt + tx];
    }
    __syncthreads();
    #pragma unroll
    for (int r = 0; r < 4; ++r) {
        int j = jt + ty + r * 8;
        out[((size_t)j * 128 + k) * 128 + it + tx] = f2bf(tile[tx][ty + r * 8]);
    }
}

// ---------------- K2: stage A GEMMs: SA[slot] (384x16384) = P(384x128)@Wprep^T --
__global__ __launch_bounds__(256) void stageA(
    const unsigned short* __restrict__ Pb,
    const unsigned short* __restrict__ Wprep, unsigned short* __restrict__ SAout)
{
    __shared__ unsigned short BL[64 * PITCH];
    int slot = blockIdx.y;
    int n0 = blockIdx.x * 64;
    const unsigned short* Wn = Wprep + (size_t)slot * 2097152 + (size_t)n0 * 128;
    unsigned short* Oo = SAout + (size_t)slot * ((size_t)384 * SAN);
    int tid = threadIdx.x;
    for (int u = tid; u < 1024; u += 256) {
        int e = u * 8; int r = e >> 7; int c = e & 127;
        *(uint4*)(&BL[r * PITCH + c]) = *(const uint4*)(&Wn[e]);
    }
    __syncthreads();
    int wave = tid >> 6, lane = tid & 63, m = lane & 15, quad = lane >> 4;
    const unsigned short* br = &BL[(wave * 16 + m) * PITCH + quad * 8];
    bf8v b0 = *(const bf8v*)(br);
    bf8v b1 = *(const bf8v*)(br + 32);
    bf8v b2 = *(const bf8v*)(br + 64);
    bf8v b3 = *(const bf8v*)(br + 96);
    for (int mt = 0; mt < 24; mt += 2) {
        const unsigned short* ar0 = Pb + (size_t)(mt * 16 + m) * 128 + quad * 8;
        const unsigned short* ar1 = ar0 + 16 * 128;
        f4v acc0 = {0.f, 0.f, 0.f, 0.f}, acc1 = {0.f, 0.f, 0.f, 0.f};
        acc0 = mfma16(*(const bf8v*)(ar0),      b0, acc0);
        acc1 = mfma16(*(const bf8v*)(ar1),      b0, acc1);
        acc0 = mfma16(*(const bf8v*)(ar0 + 32), b1, acc0);
        acc1 = mfma16(*(const bf8v*)(ar1 + 32), b1, acc1);
        acc0 = mfma16(*(const bf8v*)(ar0 + 64), b2, acc0);
        acc1 = mfma16(*(const bf8v*)(ar1 + 64), b2, acc1);
        acc0 = mfma16(*(const bf8v*)(ar0 + 96), b3, acc0);
        acc1 = mfma16(*(const bf8v*)(ar1 + 96), b3, acc1);
        unsigned short* orow0 = Oo + (size_t)(mt * 16) * SAN + n0 + wave * 16;
        unsigned short* orow1 = orow0 + (size_t)16 * SAN;
        #pragma unroll
        for (int r = 0; r < 4; ++r) {
            orow0[(size_t)(quad * 4 + r) * SAN + m] = f2bf(acc0[r]);
            orow1[(size_t)(quad * 4 + r) * SAN + m] = f2bf(acc1[r]);
        }
    }
}

// ---------------- K3: merged stage B: t=0..3 sym, t=4 ph_cop, t=5 pt_cop -------
__global__ __launch_bounds__(256) void stageB_all(
    const unsigned short* __restrict__ Pb, const unsigned short* __restrict__ SHb,
    const unsigned short* __restrict__ STb, const unsigned short* __restrict__ SA,
    float* __restrict__ out)
{
    __shared__ unsigned short WZT[128 * PITCH];
    __shared__ unsigned short Tst[64 * PITCH];
    const size_t OUTN = (size_t)2 * SS * SS * SS;

    int t  = blockIdx.y;
    int bz = blockIdx.x;
    int b  = bz / SS;
    int tid = threadIdx.x;

    // stage SA slice (32 KB) for this (t, bz)
    const unsigned short* src = SA + ((size_t)t * 384 + bz) * SAN;
    for (int u = tid; u < 2048; u += 256) {
        int e = u * 8; int j = e >> 7; int i = e & 127;
        *(uint4*)(&WZT[j * PITCH + i]) = *(const uint4*)(&src[e]);
    }
    __syncthreads();

    int wave = tid >> 6, lane = tid & 63, m = lane & 15, quad = lane >> 4;
    unsigned short* Trow = &Tst[wave * 16 * PITCH];
    const unsigned short* Ta = &Tst[(wave * 16 + m) * PITCH + quad * 8];

    if (t < 4) {
        // -------- symmetric triaffine path (block = (b, z)) --------
        const unsigned short* X = (t == 3) ? STb : SHb;
        const unsigned short* Y = (t == 2) ? SHb : STb;
        float* O = out + (size_t)t * OUTN + (size_t)bz * SS * SS;

        const int mt_tab[4][3] = {{0,7,9},{1,6,8},{2,5,10},{3,4,11}};
        const unsigned short* Xb = X + (size_t)b * SS * DD;
        const unsigned short* Yb = Y + (size_t)b * SS * DD;

        for (int mi = 0; mi < 3; ++mi) {
            int mt = mt_tab[wave][mi];
            const unsigned short* xr = Xb + (size_t)(mt * 16 + m) * DD + quad * 8;
            bf8v a[4];
            a[0] = *(const bf8v*)(xr);
            a[1] = *(const bf8v*)(xr + 32);
            a[2] = *(const bf8v*)(xr + 64);
            a[3] = *(const bf8v*)(xr + 96);

            // phase 1: T stripe (16 x 128) = X_stripe @ wz
            for (int nt = 0; nt < 8; nt += 2) {
                f4v acc0 = {0.f,0.f,0.f,0.f}, acc1 = {0.f,0.f,0.f,0.f};
                #pragma unroll
                for (int kk = 0; kk < 4; ++kk) {
                    const unsigned short* bp0 = &WZT[(nt * 16 + m) * PITCH + kk * 32 + quad * 8];
                    const unsigned short* bp1 = &WZT[((nt + 1) * 16 + m) * PITCH + kk * 32 + quad * 8];
                    acc0 = mfma16(a[kk], *(const bf8v*)bp0, acc0);
                    acc1 = mfma16(a[kk], *(const bf8v*)bp1, acc1);
                }
                #pragma unroll
                for (int r = 0; r < 4; ++r) {
                    Trow[(quad * 4 + r) * PITCH + nt * 16 + m]       = f2bf(acc0[r]);
                    Trow[(quad * 4 + r) * PITCH + (nt + 1) * 16 + m] = f2bf(acc1[r]);
                }
            }
            bf8v ta[4];
            ta[0] = *(const bf8v*)(Ta);
            ta[1] = *(const bf8v*)(Ta + 32);
            ta[2] = *(const bf8v*)(Ta + 64);
            ta[3] = *(const bf8v*)(Ta + 96);

            int xs_ = mt * 16, cc = m;
            // diagonal tile (yt == mt), per-element triangular predicate
            {
                f4v acc = {0.f,0.f,0.f,0.f};
                #pragma unroll
                for (int kk = 0; kk < 4; ++kk) {
                    bf8v bv = *(const bf8v*)(Yb + (size_t)(mt * 16 + m) * DD + kk * 32 + quad * 8);
                    acc = mfma16(ta[kk], bv, acc);
                }
                #pragma unroll
                for (int r = 0; r < 4; ++r) {
                    int rr = quad * 4 + r;
                    if (rr <= cc) O[(size_t)(xs_ + rr) * SS + xs_ + cc] = acc[r];
                    if (cc > rr)  O[(size_t)(xs_ + cc) * SS + xs_ + rr] = acc[r];
                }
            }
            // off-diagonal tiles, paired for MFMA ILP
            for (int yt = mt + 1; yt < 12; yt += 2) {
                bool pair = (yt + 1 < 12);
                const unsigned short* yb0 = Yb + (size_t)(yt * 16 + m) * DD + quad * 8;
                f4v acc0 = {0.f,0.f,0.f,0.f}, acc1 = {0.f,0.f,0.f,0.f};
                if (pair) {
                    const unsigned short* yb1 = yb0 + 16 * DD;
                    #pragma unroll
                    for (int kk = 0; kk < 4; ++kk) {
                        bf8v bv0 = *(const bf8v*)(yb0 + kk * 32);
                        bf8v bv1 = *(const bf8v*)(yb1 + kk * 32);
                        acc0 = mfma16(ta[kk], bv0, acc0);
                        acc1 = mfma16(ta[kk], bv1, acc1);
                    }
                } else {
                    #pragma unroll
                    for (int kk = 0; kk < 4; ++kk)
                        acc0 = mfma16(ta[kk], *(const bf8v*)(yb0 + kk * 32), acc0);
                }
                int ys0 = yt * 16;
                #pragma unroll
                for (int r = 0; r < 4; ++r)
                    O[(size_t)(xs_ + quad * 4 + r) * SS + ys0 + cc] = acc0[r];
                *(f4v*)(&O[(size_t)(ys0 + cc) * SS + xs_ + quad * 4]) = acc0;
                if (pair) {
                    int ys1 = ys0 + 16;
                    #pragma unroll
                    for (int r = 0; r < 4; ++r)
                        O[(size_t)(xs_ + quad * 4 + r) * SS + ys1 + cc] = acc1[r];
                    *(f4v*)(&O[(size_t)(ys1 + cc) * SS + xs_ + quad * 4]) = acc1;
                }
            }
        }
    } else {
        // -------- co-parent paths (block = (b, x)) --------
        // t==4: ph_cop, full y range, out[b,x,y,z].
        // t==5: pt_cop (symmetrized), y>=x tiles + mirror write, out[b,x,y,z].
        const unsigned short* Zsrc = (t == 4) ? SHb : STb;
        int x  = bz - b * SS;
        int xt = x >> 4;
        float* Od = out + (size_t)t * OUTN + (size_t)bz * SS * SS;          // [y][z] block base
        float* Om = out + (size_t)t * OUTN + (size_t)b * SS * SS * SS;      // mirror: +y*SS*SS + x*SS + z

        for (int zi = 0; zi < 3; ++zi) {
            int zt = wave * 3 + zi;
            const unsigned short* sr = Zsrc + (size_t)(b * SS + zt * 16 + m) * DD + quad * 8;
            bf8v a[4];
            a[0] = *(const bf8v*)(sr);
            a[1] = *(const bf8v*)(sr + 32);
            a[2] = *(const bf8v*)(sr + 64);
            a[3] = *(const bf8v*)(sr + 96);
            // phase 1: T[z,j] stripe = Z_stripe @ M
            for (int jt = 0; jt < 8; jt += 2) {
                f4v acc0 = {0.f,0.f,0.f,0.f}, acc1 = {0.f,0.f,0.f,0.f};
                #pragma unroll
                for (int kk = 0; kk < 4; ++kk) {
                    const unsigned short* bp0 = &WZT[(jt * 16 + m) * PITCH + kk * 32 + quad * 8];
                    const unsigned short* bp1 = &WZT[((jt + 1) * 16 + m) * PITCH + kk * 32 + quad * 8];
                    acc0 = mfma16(a[kk], *(const bf8v*)bp0, acc0);
                    acc1 = mfma16(a[kk], *(const bf8v*)bp1, acc1);
                }
                #pragma unroll
                for (int r = 0; r < 4; ++r) {
                    Trow[(quad * 4 + r) * PITCH + jt * 16 + m]       = f2bf(acc0[r]);
                    Trow[(quad * 4 + r) * PITCH + (jt + 1) * 16 + m] = f2bf(acc1[r]);
                }
            }
            // T stripe as B-fragments (n = z)
            bf8v tb[4];
            tb[0] = *(const bf8v*)(Ta);
            tb[1] = *(const bf8v*)(Ta + 32);
            tb[2] = *(const bf8v*)(Ta + 64);
            tb[3] = *(const bf8v*)(Ta + 96);

            const unsigned short* Pbase = Pb + (size_t)b * SS * DD;
            int zc = zt * 16 + m;

            if (t == 4) {
                // full y range, paired
                for (int yt = 0; yt < 12; yt += 2) {
                    const unsigned short* p0 = Pbase + (size_t)(yt * 16 + m) * DD + quad * 8;
                    const unsigned short* p1 = p0 + 16 * DD;
                    f4v acc0 = {0.f,0.f,0.f,0.f}, acc1 = {0.f,0.f,0.f,0.f};
                    #pragma unroll
                    for (int kk = 0; kk < 4; ++kk) {
                        bf8v av0 = *(const bf8v*)(p0 + kk * 32);
                        bf8v av1 = *(const bf8v*)(p1 + kk * 32);
                        acc0 = mfma16(av0, tb[kk], acc0);
                        acc1 = mfma16(av1, tb[kk], acc1);
                    }
                    #pragma unroll
                    for (int r = 0; r < 4; ++r) {
                        Od[(size_t)(yt * 16 + quad * 4 + r) * SS + zc]       = acc0[r];
                        Od[(size_t)((yt + 1) * 16 + quad * 4 + r) * SS + zc] = acc1[r];
                    }
                }
            } else {
                // diagonal tile (yt == xt): per-element predicate on y vs x
                {
                    const unsigned short* p0 = Pbase + (size_t)(xt * 16 + m) * DD + quad * 8;
                    f4v acc = {0.f,0.f,0.f,0.f};
                    #pragma unroll
                    for (int kk = 0; kk < 4; ++kk)
                        acc = mfma16(*(const bf8v*)(p0 + kk * 32), tb[kk], acc);
                    #pragma unroll
                    for (int r = 0; r < 4; ++r) {
                        int y = xt * 16 + quad * 4 + r;
                        if (y >= x) Od[(size_t)y * SS + zc] = acc[r];
                        if (y > x)  Om[(size_t)y * SS * SS + (size_t)x * SS + zc] = acc[r];
                    }
                }
                // y tiles above the diagonal, paired, direct + mirror stores
                for (int yt = xt + 1; yt < 12; yt += 2) {
                    bool pair = (yt + 1 < 12);
                    const unsigned short* p0 = Pbase + (size_t)(yt * 16 + m) * DD + quad * 8;
                    f4v acc0 = {0.f,0.f,0.f,0.f}, acc1 = {0.f,0.f,0.f,0.f};
                    if (pair) {
                        const unsigned short* p1 = p0 + 16 * DD;
                        #pragma unroll
                        for (int kk = 0; kk < 4; ++kk) {
                            bf8v av0 = *(const bf8v*)(p0 + kk * 32);
                            bf8v av1 = *(const bf8v*)(p1 + kk * 32);
                            acc0 = mfma16(av0, tb[kk], acc0);
                            acc1 = mfma16(av1, tb[kk], acc1);
                        }
                    } else {
                        #pragma unroll
                        for (int kk = 0; kk < 4; ++kk)
                            acc0 = mfma16(*(const bf8v*)(p0 + kk * 32), tb[kk], acc0);
                    }
                    #pragma unroll
                    for (int r = 0; r < 4; ++r) {
                        int y0 = yt * 16 + quad * 4 + r;
                        Od[(size_t)y0 * SS + zc] = acc0[r];
                        Om[(size_t)y0 * SS * SS + (size_t)x * SS + zc] = acc0[r];
                    }
                    if (pair) {
                        #pragma unroll
                        for (int r = 0; r < 4; ++r) {
                            int y1 = (yt + 1) * 16 + quad * 4 + r;
                            Od[(size_t)y1 * SS + zc] = acc1[r];
                            Om[(size_t)y1 * SS * SS + (size_t)x * SS + zc] = acc1[r];
                        }
                    }
                }
            }
        }
    }
}

extern "C" void kernel_launch(void* const* d_in, const int* in_sizes, int n_in,
                              void* d_out, int out_size, void* d_ws, size_t ws_size,
                              hipStream_t stream)
{
    const float* x   = (const float*)d_in[0];
    const float* Wp  = (const float*)d_in[1];
    const float* bp  = (const float*)d_in[2];
    const float* Wh  = (const float*)d_in[3];
    const float* bh  = (const float*)d_in[4];
    const float* Wt  = (const float*)d_in[5];
    const float* bt  = (const float*)d_in[6];
    const float* W_span_ph = (const float*)d_in[7];
    const float* W_span_pt = (const float*)d_in[8];
    const float* W_ph_sib  = (const float*)d_in[9];
    const float* W_pt_sib  = (const float*)d_in[10];
    const float* W_ph_cop  = (const float*)d_in[11];
    const float* W_pt_cop  = (const float*)d_in[12];

    char* ws = (char*)d_ws;
    unsigned short* Pb    = (unsigned short*)ws;                 // 98304 B
    unsigned short* SHb   = Pb + 384 * 128;
    unsigned short* STb   = SHb + 384 * 128;
    unsigned short* Wprep = (unsigned short*)(ws + 294912);      // 6 x 4 MiB bf16
    unsigned short* SA    = (unsigned short*)(ws + 294912 + (size_t)6 * 2097152 * 2);

    float* out  = (float*)d_out;

    proj_kernel<<<dim3(48, 3), 256, 0, stream>>>(x, Wp, bp, Wh, bh, Wt, bt, Pb, SHb, STb);
    prep_rev<<<dim3(16, 128, 4), 256, 0, stream>>>(W_span_ph, W_span_pt, W_ph_sib,
                                                   W_pt_sib, Wprep);
    prep_cop<<<dim3(16, 128, 2), 256, 0, stream>>>(W_ph_cop, W_pt_cop, Wprep);
    stageA<<<dim3(256, 6), 256, 0, stream>>>(Pb, Wprep, SA);
    stageB_all<<<dim3(384, 6), 256, 0, stream>>>(Pb, SHb, STb, SA, out);
}

// Round 3
// 563.602 us; speedup vs baseline: 1.1744x; 1.1372x over previous
//
#include <hip/hip_runtime.h>

#define SS 192
#define DD 128
#define SAN 16384                     // stage-A row length (128*128)
#define PITCH 136                     // LDS row pitch in bf16 elements (272B, 16B-aligned, conflict-safe)

typedef short bf8v __attribute__((ext_vector_type(8)));   // 8 x bf16
typedef float f4v  __attribute__((ext_vector_type(4)));

__device__ __forceinline__ unsigned short f2bf(float f) {
    union { float f; unsigned u; } v; v.f = f;
    unsigned r = v.u + 0x7fffu + ((v.u >> 16) & 1u);
    return (unsigned short)(r >> 16);
}

__device__ __forceinline__ f4v mfma16(bf8v a, bf8v b, f4v c) {
    return __builtin_amdgcn_mfma_f32_16x16x32_bf16(a, b, c, 0, 0, 0);
}

// ---------------- K0a: MLP projections, K-chunked partials (f32) ---------------
// grid (48, 3, 4): 8 rows x 128 cols per block, K-chunk of 256.
__global__ __launch_bounds__(256) void proj_part(
    const float* __restrict__ x,
    const float* __restrict__ Wp, const float* __restrict__ Wh,
    const float* __restrict__ Wt, float* __restrict__ part)
{
    __shared__ float xs[8 * 256];
    int r0 = blockIdx.x * 8;
    int w  = blockIdx.y;
    int kc = blockIdx.z;
    const float* W = (w == 0) ? Wp : (w == 1) ? Wh : Wt;
    int tid = threadIdx.x;
    for (int u = tid; u < 512; u += 256) {
        int row = u >> 6, k4 = u & 63;
        *(float4*)(&xs[row * 256 + k4 * 4]) =
            *(const float4*)(&x[(size_t)(r0 + row) * 1024 + kc * 256 + k4 * 4]);
    }
    __syncthreads();
    int col = tid & 127, rg = tid >> 7;
    float acc[4] = {0.f, 0.f, 0.f, 0.f};
    const float* Wk = W + (size_t)(kc * 256) * 128 + col;
    #pragma unroll 8
    for (int k = 0; k < 256; ++k) {
        float wv = Wk[(size_t)k * 128];
        #pragma unroll
        for (int r = 0; r < 4; ++r) acc[r] += xs[(rg * 4 + r) * 256 + k] * wv;
    }
    float* pp = part + (((size_t)w * 4 + kc) * 384) * 128;
    #pragma unroll
    for (int r = 0; r < 4; ++r)
        pp[(size_t)(r0 + rg * 4 + r) * 128 + col] = acc[r];
}

// ---------------- K0b: finalize: sum 4 partials + bias + leaky + bf16 ----------
__global__ __launch_bounds__(256) void proj_fin(
    const float* __restrict__ part,
    const float* __restrict__ bp, const float* __restrict__ bh,
    const float* __restrict__ bt,
    unsigned short* __restrict__ Pb, unsigned short* __restrict__ SHb,
    unsigned short* __restrict__ STb)
{
    int r0 = blockIdx.x * 8;
    int w  = blockIdx.y;
    const float* bias = (w == 0) ? bp : (w == 1) ? bh : bt;
    unsigned short* O = (w == 0) ? Pb : (w == 1) ? SHb : STb;
    int tid = threadIdx.x;
    int col = tid & 127, rg = tid >> 7;
    const float* pw = part + ((size_t)w * 4) * 384 * 128;
    float bb = bias[col];
    #pragma unroll
    for (int r = 0; r < 4; ++r) {
        int row = r0 + rg * 4 + r;
        float s = pw[(size_t)row * 128 + col]
                + pw[(size_t)(384 + row) * 128 + col]
                + pw[(size_t)(2 * 384 + row) * 128 + col]
                + pw[(size_t)(3 * 384 + row) * 128 + col];
        s += bb;
        s = s > 0.f ? s : 0.1f * s;
        O[(size_t)row * 128 + col] = f2bf(s);
    }
}

// ---------------- K1a: W[i][k][j] -> Wprep[j][i][k] (bf16), slots 0..3 ----------
__global__ __launch_bounds__(256) void prep_rev(
    const float* __restrict__ w0, const float* __restrict__ w1,
    const float* __restrict__ w2, const float* __restrict__ w3,
    unsigned short* __restrict__ Wprep)
{
    __shared__ float tile[32][33];
    int sel = blockIdx.z;
    const float* in = (sel == 0) ? w0 : (sel == 1) ? w1 : (sel == 2) ? w2 : w3;
    unsigned short* out = Wprep + (size_t)sel * 2097152;
    int i  = blockIdx.y;
    int kt = (blockIdx.x >> 2) * 32, jt = (blockIdx.x & 3) * 32;
    int tx = threadIdx.x & 31, ty = threadIdx.x >> 5;
    #pragma unroll
    for (int r = 0; r < 4; ++r) {
        int k = kt + ty + r * 8;
        tile[ty + r * 8][tx] = in[((size_t)i * 128 + k) * 128 + jt + tx];
    }
    __syncthreads();
    #pragma unroll
    for (int r = 0; r < 4; ++r) {
        int j = jt + ty + r * 8;
        out[((size_t)j * 128 + i) * 128 + kt + tx] = f2bf(tile[tx][ty + r * 8]);
    }
}

// ---------------- K1b: W[i][k][j] -> Wprep[j][k][i] (bf16), slots 4 (ph), 5 (pt)
__global__ __launch_bounds__(256) void prep_cop(
    const float* __restrict__ in0, const float* __restrict__ in1,
    unsigned short* __restrict__ Wprep)
{
    __shared__ float tile[32][33];
    int sel = blockIdx.z;
    const float* in = sel ? in1 : in0;
    unsigned short* out = Wprep + (size_t)(4 + sel) * 2097152;
    int k  = blockIdx.y;
    int it = (blockIdx.x >> 2) * 32, jt = (blockIdx.x & 3) * 32;
    int tx = threadIdx.x & 31, ty = threadIdx.x >> 5;
    #pragma unroll
    for (int r = 0; r < 4; ++r) {
        int i = it + ty + r * 8;
        tile[ty + r * 8][tx] = in[((size_t)i * 128 + k) * 128 + jt + tx];
    }
    __syncthreads();
    #pragma unroll
    for (int r = 0; r < 4; ++r) {
        int j = jt + ty + r * 8;
        out[((size_t)j * 128 + k) * 128 + it + tx] = f2bf(tile[tx][ty + r * 8]);
    }
}

// ---------------- K2: stage A GEMMs: SA[slot] (384x16384) = P(384x128)@Wprep^T --
__global__ __launch_bounds__(256) void stageA(
    const unsigned short* __restrict__ Pb,
    const unsigned short* __restrict__ Wprep, unsigned short* __restrict__ SAout)
{
    __shared__ unsigned short BL[64 * PITCH];
    int slot = blockIdx.y;
    int n0 = blockIdx.x * 64;
    const unsigned short* Wn = Wprep + (size_t)slot * 2097152 + (size_t)n0 * 128;
    unsigned short* Oo = SAout + (size_t)slot * ((size_t)384 * SAN);
    int tid = threadIdx.x;
    for (int u = tid; u < 1024; u += 256) {
        int e = u * 8; int r = e >> 7; int c = e & 127;
        *(uint4*)(&BL[r * PITCH + c]) = *(const uint4*)(&Wn[e]);
    }
    __syncthreads();
    int wave = tid >> 6, lane = tid & 63, m = lane & 15, quad = lane >> 4;
    const unsigned short* br = &BL[(wave * 16 + m) * PITCH + quad * 8];
    bf8v b0 = *(const bf8v*)(br);
    bf8v b1 = *(const bf8v*)(br + 32);
    bf8v b2 = *(const bf8v*)(br + 64);
    bf8v b3 = *(const bf8v*)(br + 96);
    for (int mt = 0; mt < 24; mt += 2) {
        const unsigned short* ar0 = Pb + (size_t)(mt * 16 + m) * 128 + quad * 8;
        const unsigned short* ar1 = ar0 + 16 * 128;
        f4v acc0 = {0.f, 0.f, 0.f, 0.f}, acc1 = {0.f, 0.f, 0.f, 0.f};
        acc0 = mfma16(*(const bf8v*)(ar0),      b0, acc0);
        acc1 = mfma16(*(const bf8v*)(ar1),      b0, acc1);
        acc0 = mfma16(*(const bf8v*)(ar0 + 32), b1, acc0);
        acc1 = mfma16(*(const bf8v*)(ar1 + 32), b1, acc1);
        acc0 = mfma16(*(const bf8v*)(ar0 + 64), b2, acc0);
        acc1 = mfma16(*(const bf8v*)(ar1 + 64), b2, acc1);
        acc0 = mfma16(*(const bf8v*)(ar0 + 96), b3, acc0);
        acc1 = mfma16(*(const bf8v*)(ar1 + 96), b3, acc1);
        unsigned short* orow0 = Oo + (size_t)(mt * 16) * SAN + n0 + wave * 16;
        unsigned short* orow1 = orow0 + (size_t)16 * SAN;
        #pragma unroll
        for (int r = 0; r < 4; ++r) {
            orow0[(size_t)(quad * 4 + r) * SAN + m] = f2bf(acc0[r]);
            orow1[(size_t)(quad * 4 + r) * SAN + m] = f2bf(acc1[r]);
        }
    }
}

// ---------------- K3: merged stage B: t=0..3 sym, t=4 ph_cop, t=5 pt_cop -------
// phase 1 builds all per-wave T-stripe fragments into registers (ta/tb[3][4]),
// phase 2 is yt-outer: one Y/P fragment load feeds up to 3 independent MFMA
// chains (12 MFMA per load-batch) to hide L2 latency.
__global__ __launch_bounds__(256, 3) void stageB_all(
    const unsigned short* __restrict__ Pb, const unsigned short* __restrict__ SHb,
    const unsigned short* __restrict__ STb, const unsigned short* __restrict__ SA,
    float* __restrict__ out)
{
    __shared__ unsigned short WZT[128 * PITCH];
    __shared__ unsigned short Tst[64 * PITCH];
    const size_t OUTN = (size_t)2 * SS * SS * SS;

    int t  = blockIdx.y;
    int bz = blockIdx.x;
    int b  = bz / SS;
    int tid = threadIdx.x;

    // stage SA slice (32 KB) for this (t, bz)
    const unsigned short* src = SA + ((size_t)t * 384 + bz) * SAN;
    for (int u = tid; u < 2048; u += 256) {
        int e = u * 8; int j = e >> 7; int i = e & 127;
        *(uint4*)(&WZT[j * PITCH + i]) = *(const uint4*)(&src[e]);
    }
    __syncthreads();

    int wave = tid >> 6, lane = tid & 63, m = lane & 15, quad = lane >> 4;
    unsigned short* Trow = &Tst[wave * 16 * PITCH];
    const unsigned short* Ta = &Tst[(wave * 16 + m) * PITCH + quad * 8];

    if (t < 4) {
        // -------- symmetric triaffine path (block = (b, z)) --------
        const unsigned short* X = (t == 3) ? STb : SHb;
        const unsigned short* Y = (t == 2) ? SHb : STb;
        float* O = out + (size_t)t * OUTN + (size_t)bz * SS * SS;
        const unsigned short* Xb = X + (size_t)b * SS * DD;
        const unsigned short* Yb = Y + (size_t)b * SS * DD;

        // balanced upper-triangle m-tile assignment: {0,7,9},{1,6,8},{2,5,10},{3,4,11}
        int mts[3];
        mts[0] = wave;
        mts[1] = 7 - wave;
        mts[2] = (wave < 2) ? 9 - wave : 8 + wave;

        bf8v ta[3][4];
        #pragma unroll
        for (int mi = 0; mi < 3; ++mi) {
            int mt = mts[mi];
            const unsigned short* xr = Xb + (size_t)(mt * 16 + m) * DD + quad * 8;
            bf8v a0 = *(const bf8v*)(xr);
            bf8v a1 = *(const bf8v*)(xr + 32);
            bf8v a2 = *(const bf8v*)(xr + 64);
            bf8v a3 = *(const bf8v*)(xr + 96);
            // phase 1: T stripe (16 x 128) = X_stripe @ wz
            for (int nt = 0; nt < 8; nt += 2) {
                f4v acc0 = {0.f,0.f,0.f,0.f}, acc1 = {0.f,0.f,0.f,0.f};
                const unsigned short* w0 = &WZT[(nt * 16 + m) * PITCH + quad * 8];
                const unsigned short* w1 = &WZT[((nt + 1) * 16 + m) * PITCH + quad * 8];
                acc0 = mfma16(a0, *(const bf8v*)(w0),      acc0);
                acc1 = mfma16(a0, *(const bf8v*)(w1),      acc1);
                acc0 = mfma16(a1, *(const bf8v*)(w0 + 32), acc0);
                acc1 = mfma16(a1, *(const bf8v*)(w1 + 32), acc1);
                acc0 = mfma16(a2, *(const bf8v*)(w0 + 64), acc0);
                acc1 = mfma16(a2, *(const bf8v*)(w1 + 64), acc1);
                acc0 = mfma16(a3, *(const bf8v*)(w0 + 96), acc0);
                acc1 = mfma16(a3, *(const bf8v*)(w1 + 96), acc1);
                #pragma unroll
                for (int r = 0; r < 4; ++r) {
                    Trow[(quad * 4 + r) * PITCH + nt * 16 + m]       = f2bf(acc0[r]);
                    Trow[(quad * 4 + r) * PITCH + (nt + 1) * 16 + m] = f2bf(acc1[r]);
                }
            }
            ta[mi][0] = *(const bf8v*)(Ta);
            ta[mi][1] = *(const bf8v*)(Ta + 32);
            ta[mi][2] = *(const bf8v*)(Ta + 64);
            ta[mi][3] = *(const bf8v*)(Ta + 96);
        }

        // phase 2: yt-outer; one Y-frag load feeds up to 3 tiles
        for (int yt = mts[0]; yt < 12; ++yt) {
            const unsigned short* yr = Yb + (size_t)(yt * 16 + m) * DD + quad * 8;
            bf8v yv0 = *(const bf8v*)(yr);
            bf8v yv1 = *(const bf8v*)(yr + 32);
            bf8v yv2 = *(const bf8v*)(yr + 64);
            bf8v yv3 = *(const bf8v*)(yr + 96);
            f4v accs[3];
            #pragma unroll
            for (int mi = 0; mi < 3; ++mi) {
                f4v acc = {0.f,0.f,0.f,0.f};
                acc = mfma16(ta[mi][0], yv0, acc);
                acc = mfma16(ta[mi][1], yv1, acc);
                acc = mfma16(ta[mi][2], yv2, acc);
                acc = mfma16(ta[mi][3], yv3, acc);
                accs[mi] = acc;
            }
            #pragma unroll
            for (int mi = 0; mi < 3; ++mi) {
                int mt = mts[mi];
                if (mt > yt) continue;          // wave-uniform guard: tile not owned
                f4v acc = accs[mi];
                int xs_ = mt * 16, ys_ = yt * 16, cc = m;
                if (mt == yt) {
                    #pragma unroll
                    for (int r = 0; r < 4; ++r) {
                        int rr = quad * 4 + r;
                        if (rr <= cc) O[(size_t)(xs_ + rr) * SS + xs_ + cc] = acc[r];
                        if (cc > rr)  O[(size_t)(xs_ + cc) * SS + xs_ + rr] = acc[r];
                    }
                } else {
                    #pragma unroll
                    for (int r = 0; r < 4; ++r)
                        O[(size_t)(xs_ + quad * 4 + r) * SS + ys_ + cc] = acc[r];
                    *(f4v*)(&O[(size_t)(ys_ + cc) * SS + xs_ + quad * 4]) = acc;
                }
            }
        }
    } else {
        // -------- co-parent paths (block = (b, x)) --------
        const unsigned short* Zsrc = (t == 4) ? SHb : STb;
        int x  = bz - b * SS;
        int xt = x >> 4;
        float* Od = out + (size_t)t * OUTN + (size_t)bz * SS * SS;          // [y][z]
        float* Om = out + (size_t)t * OUTN + (size_t)b * SS * SS * SS;      // mirror base

        bf8v tb[3][4];
        #pragma unroll
        for (int zi = 0; zi < 3; ++zi) {
            int zt = wave * 3 + zi;
            const unsigned short* sr = Zsrc + (size_t)(b * SS + zt * 16 + m) * DD + quad * 8;
            bf8v a0 = *(const bf8v*)(sr);
            bf8v a1 = *(const bf8v*)(sr + 32);
            bf8v a2 = *(const bf8v*)(sr + 64);
            bf8v a3 = *(const bf8v*)(sr + 96);
            // phase 1: T[z,j] stripe = Z_stripe @ M
            for (int jt = 0; jt < 8; jt += 2) {
                f4v acc0 = {0.f,0.f,0.f,0.f}, acc1 = {0.f,0.f,0.f,0.f};
                const unsigned short* w0 = &WZT[(jt * 16 + m) * PITCH + quad * 8];
                const unsigned short* w1 = &WZT[((jt + 1) * 16 + m) * PITCH + quad * 8];
                acc0 = mfma16(a0, *(const bf8v*)(w0),      acc0);
                acc1 = mfma16(a0, *(const bf8v*)(w1),      acc1);
                acc0 = mfma16(a1, *(const bf8v*)(w0 + 32), acc0);
                acc1 = mfma16(a1, *(const bf8v*)(w1 + 32), acc1);
                acc0 = mfma16(a2, *(const bf8v*)(w0 + 64), acc0);
                acc1 = mfma16(a2, *(const bf8v*)(w1 + 64), acc1);
                acc0 = mfma16(a3, *(const bf8v*)(w0 + 96), acc0);
                acc1 = mfma16(a3, *(const bf8v*)(w1 + 96), acc1);
                #pragma unroll
                for (int r = 0; r < 4; ++r) {
                    Trow[(quad * 4 + r) * PITCH + jt * 16 + m]       = f2bf(acc0[r]);
                    Trow[(quad * 4 + r) * PITCH + (jt + 1) * 16 + m] = f2bf(acc1[r]);
                }
            }
            tb[zi][0] = *(const bf8v*)(Ta);
            tb[zi][1] = *(const bf8v*)(Ta + 32);
            tb[zi][2] = *(const bf8v*)(Ta + 64);
            tb[zi][3] = *(const bf8v*)(Ta + 96);
        }

        const unsigned short* Pbase = Pb + (size_t)b * SS * DD;
        int yt0 = (t == 4) ? 0 : xt;
        for (int yt = yt0; yt < 12; ++yt) {
            const unsigned short* pr = Pbase + (size_t)(yt * 16 + m) * DD + quad * 8;
            bf8v pv0 = *(const bf8v*)(pr);
            bf8v pv1 = *(const bf8v*)(pr + 32);
            bf8v pv2 = *(const bf8v*)(pr + 64);
            bf8v pv3 = *(const bf8v*)(pr + 96);
            f4v accs[3];
            #pragma unroll
            for (int zi = 0; zi < 3; ++zi) {
                f4v acc = {0.f,0.f,0.f,0.f};
                acc = mfma16(pv0, tb[zi][0], acc);
                acc = mfma16(pv1, tb[zi][1], acc);
                acc = mfma16(pv2, tb[zi][2], acc);
                acc = mfma16(pv3, tb[zi][3], acc);
                accs[zi] = acc;
            }
            if (t == 4) {
                #pragma unroll
                for (int zi = 0; zi < 3; ++zi) {
                    int zc = (wave * 3 + zi) * 16 + m;
                    #pragma unroll
                    for (int r = 0; r < 4; ++r)
                        Od[(size_t)(yt * 16 + quad * 4 + r) * SS + zc] = accs[zi][r];
                }
            } else if (yt == xt) {
                // diagonal tile: per-element predicate on y vs x
                #pragma unroll
                for (int zi = 0; zi < 3; ++zi) {
                    int zc = (wave * 3 + zi) * 16 + m;
                    #pragma unroll
                    for (int r = 0; r < 4; ++r) {
                        int y = yt * 16 + quad * 4 + r;
                        if (y >= x) Od[(size_t)y * SS + zc] = accs[zi][r];
                        if (y > x)  Om[(size_t)y * SS * SS + (size_t)x * SS + zc] = accs[zi][r];
                    }
                }
            } else {
                #pragma unroll
                for (int zi = 0; zi < 3; ++zi) {
                    int zc = (wave * 3 + zi) * 16 + m;
                    #pragma unroll
                    for (int r = 0; r < 4; ++r) {
                        int y = yt * 16 + quad * 4 + r;
                        Od[(size_t)y * SS + zc] = accs[zi][r];
                        Om[(size_t)y * SS * SS + (size_t)x * SS + zc] = accs[zi][r];
                    }
                }
            }
        }
    }
}

extern "C" void kernel_launch(void* const* d_in, const int* in_sizes, int n_in,
                              void* d_out, int out_size, void* d_ws, size_t ws_size,
                              hipStream_t stream)
{
    const float* x   = (const float*)d_in[0];
    const float* Wp  = (const float*)d_in[1];
    const float* bp  = (const float*)d_in[2];
    const float* Wh  = (const float*)d_in[3];
    const float* bh  = (const float*)d_in[4];
    const float* Wt  = (const float*)d_in[5];
    const float* bt  = (const float*)d_in[6];
    const float* W_span_ph = (const float*)d_in[7];
    const float* W_span_pt = (const float*)d_in[8];
    const float* W_ph_sib  = (const float*)d_in[9];
    const float* W_pt_sib  = (const float*)d_in[10];
    const float* W_ph_cop  = (const float*)d_in[11];
    const float* W_pt_cop  = (const float*)d_in[12];

    char* ws = (char*)d_ws;
    unsigned short* Pb    = (unsigned short*)ws;                 // 98304 B
    unsigned short* SHb   = Pb + 384 * 128;
    unsigned short* STb   = SHb + 384 * 128;
    unsigned short* Wprep = (unsigned short*)(ws + 294912);      // 6 x 4 MiB bf16
    unsigned short* SA    = (unsigned short*)(ws + 294912 + (size_t)6 * 2097152 * 2);
    float* part = (float*)SA;   // proj partials (2.36 MB) overlay SA region;
                                // consumed by proj_fin before stageA writes SA

    float* out  = (float*)d_out;

    proj_part<<<dim3(48, 3, 4), 256, 0, stream>>>(x, Wp, Wh, Wt, part);
    proj_fin<<<dim3(48, 3), 256, 0, stream>>>(part, bp, bh, bt, Pb, SHb, STb);
    prep_rev<<<dim3(16, 128, 4), 256, 0, stream>>>(W_span_ph, W_span_pt, W_ph_sib,
                                                   W_pt_sib, Wprep);
    prep_cop<<<dim3(16, 128, 2), 256, 0, stream>>>(W_ph_cop, W_pt_cop, Wprep);
    stageA<<<dim3(256, 6), 256, 0, stream>>>(Pb, Wprep, SA);
    stageB_all<<<dim3(384, 6), 256, 0, stream>>>(Pb, SHb, STb, SA, out);
}